// Round 3
// baseline (46.368 us; speedup 1.0000x reference)
//
#include <hip/hip_runtime.h>
#include <math.h>

constexpr int NXc = 256, NYc = 256, ETLc = 16, NTc = 100, NBc = 30;
constexpr int NPIX = NXc * NYc;
constexpr int TCHUNK = 25;          // T2 atoms per block (100 = 4 chunks of 25)

// ws layout: [0 .. NT*256)  -> f1 block partials  ws_f1[t*256 + pixblk]
//            [NT*256 .. +256) -> f2 block partials ws_f2[pixblk]

__global__ __launch_bounds__(256) void dm_main(
    const float* __restrict__ sig,      // [NPIX][16]
    const float* __restrict__ db_mag,   // [100][30][16]
    const float* __restrict__ db_b1s,   // [30]
    const float* __restrict__ dtt,      // [16]
    const float* __restrict__ est,      // [2][NPIX]
    float* __restrict__ ws_f1,          // [100][256]
    float* __restrict__ ws_f2)          // [256]
{
    const int tid    = threadIdx.x;
    const int pixblk = blockIdx.x & 255;
    const int tchunk = blockIdx.x >> 8;
    const int p = (pixblk << 8) | tid;
    const int x = p >> 8;
    const int y = p & 255;

    __shared__ float s_part[TCHUNK * 4];
    __shared__ float s_f2[4];

    // --- load & normalize signal (16 floats, 64B aligned) ---
    const float4* sp = reinterpret_cast<const float4*>(sig + (size_t)p * ETLc);
    float s[16];
    {
        float4 a = sp[0], b = sp[1], c = sp[2], d = sp[3];
        s[0]=a.x; s[1]=a.y; s[2]=a.z;  s[3]=a.w;
        s[4]=b.x; s[5]=b.y; s[6]=b.z;  s[7]=b.w;
        s[8]=c.x; s[9]=c.y; s[10]=c.z; s[11]=c.w;
        s[12]=d.x; s[13]=d.y; s[14]=d.z; s[15]=d.w;
    }
    float snrm2 = 0.f;
#pragma unroll
    for (int e = 0; e < 16; ++e) snrm2 = fmaf(s[e], s[e], snrm2);
    const float sig2  = (snrm2 > 0.f) ? 1.0f : 0.0f;
    const float srinv = (snrm2 > 0.f) ? (1.0f / sqrtf(snrm2)) : 0.0f;
    float sgn[16];
#pragma unroll
    for (int e = 0; e < 16; ++e) sgn[e] = s[e] * srinv;

    // --- eta = exp(-dt/t2p) ---
    const float est0 = est[p];
    const float t2p  = 1.0f + 499.0f * est0;
    float eta[16];
#pragma unroll
    for (int e = 0; e < 16; ++e) eta[e] = expf(-dtt[e] / t2p);

    // --- nearest b1 grid index (argmin, first occurrence on tie) ---
    const float est1 = est[NPIX + p];
    const float b1   = 0.2f + 1.4f * est1;
    int jb = 0; float best = 3.4e38f;
    for (int k = 0; k < NBc; ++k) {
        float d = b1 - db_b1s[k];
        d = d * d;
        if (d < best) { best = d; jb = k; }
    }

    const int wid = tid >> 6, lane = tid & 63;
    const int t0  = tchunk * TCHUNK;
    const float* dbbase = db_mag + ((size_t)t0 * NBc + jb) * ETLc;

#pragma unroll 1
    for (int tt = 0; tt < TCHUNK; ++tt) {
        const float4* dp = reinterpret_cast<const float4*>(dbbase + (size_t)tt * (NBc * ETLc));
        float dbr[16];
        {
            float4 a = dp[0], b = dp[1], c = dp[2], d = dp[3];
            dbr[0]=a.x; dbr[1]=a.y; dbr[2]=a.z;  dbr[3]=a.w;
            dbr[4]=b.x; dbr[5]=b.y; dbr[6]=b.z;  dbr[7]=b.w;
            dbr[8]=c.x; dbr[9]=c.y; dbr[10]=c.z; dbr[11]=c.w;
            dbr[12]=d.x; dbr[13]=d.y; dbr[14]=d.z; dbr[15]=d.w;
        }
        float nrm2 = 0.f, dotv = 0.f;
#pragma unroll
        for (int e = 0; e < 16; ++e) {
            float v = dbr[e] * eta[e];
            nrm2 = fmaf(v, v, nrm2);
            dotv = fmaf(v, sgn[e], dotv);
        }
        float l2sq;
        if (nrm2 > 0.f) l2sq = sig2 + 1.0f - 2.0f * dotv * (1.0f / sqrtf(nrm2));
        else            l2sq = sig2;
        if (l2sq < 0.f) l2sq = 0.f;

        // deterministic wave reduce (64 lanes) then per-wave LDS slot
        float r = l2sq;
#pragma unroll
        for (int m = 32; m; m >>= 1) r += __shfl_xor(r, m, 64);
        if (lane == 0) s_part[tt * 4 + wid] = r;
    }
    __syncthreads();
    if (tid < TCHUNK) {
        float bsum = s_part[tid*4+0] + s_part[tid*4+1] + s_part[tid*4+2] + s_part[tid*4+3];
        ws_f1[(size_t)(t0 + tid) * 256 + pixblk] = bsum;
    }

    // --- f2 (TV of b1) — computed once, by the tchunk==0 blocks ---
    if (tchunk == 0) {
        const float* e1 = est + NPIX;
        float g0, g1;
        {
            float c = b1;
            if (x == 0)            g0 = (0.2f + 1.4f * e1[p + 256]) - c;
            else if (x == NXc - 1) g0 = c - (0.2f + 1.4f * e1[p - 256]);
            else                   g0 = 0.5f * ((0.2f + 1.4f * e1[p + 256]) - (0.2f + 1.4f * e1[p - 256]));
            if (y == 0)            g1 = (0.2f + 1.4f * e1[p + 1]) - c;
            else if (y == NYc - 1) g1 = c - (0.2f + 1.4f * e1[p - 1]);
            else                   g1 = 0.5f * ((0.2f + 1.4f * e1[p + 1]) - (0.2f + 1.4f * e1[p - 1]));
        }
        float r = fabsf(g0) + fabsf(g1);
#pragma unroll
        for (int m = 32; m; m >>= 1) r += __shfl_xor(r, m, 64);
        if (lane == 0) s_f2[wid] = r;
        __syncthreads();
        if (tid == 0) ws_f2[pixblk] = s_f2[0] + s_f2[1] + s_f2[2] + s_f2[3];
    }
}

__global__ __launch_bounds__(128) void dm_final(
    const float* __restrict__ ws_f1,   // [100][256]
    const float* __restrict__ ws_f2,   // [256]
    float* __restrict__ out)
{
    const int tid = threadIdx.x;  // 128 threads
    float v = 0.f;
    if (tid < NTc) {
        float sum = 0.f;
        for (int b = 0; b < 256; ++b) sum += ws_f1[(size_t)tid * 256 + b];
        v = sqrtf(sum);
    }
    v += ws_f2[tid] + ws_f2[tid + 128];

    // reduce 128 threads: wave reduce then combine 2 waves
#pragma unroll
    for (int m = 32; m; m >>= 1) v += __shfl_xor(v, m, 64);
    __shared__ float sred[2];
    if ((tid & 63) == 0) sred[tid >> 6] = v;
    __syncthreads();
    if (tid == 0) out[0] = sred[0] + sred[1];
}

extern "C" void kernel_launch(void* const* d_in, const int* in_sizes, int n_in,
                              void* d_out, int out_size, void* d_ws, size_t ws_size,
                              hipStream_t stream) {
    const float* sig    = (const float*)d_in[0];  // slice_signal (256,256,16)
    const float* db_mag = (const float*)d_in[1];  // (100,30,16)
    // d_in[2] = db_t2s_ms — unused by the reference
    const float* db_b1s = (const float*)d_in[3];  // (30,)
    const float* dtt    = (const float*)d_in[4];  // (16,)
    const float* est    = (const float*)d_in[5];  // (2,256,256)
    float* out = (float*)d_out;

    float* ws_f1 = (float*)d_ws;                  // [100][256]
    float* ws_f2 = ws_f1 + (size_t)NTc * 256;     // [256]

    dm_main<<<dim3(256 * 4), dim3(256), 0, stream>>>(sig, db_mag, db_b1s, dtt, est, ws_f1, ws_f2);
    dm_final<<<dim3(1), dim3(128), 0, stream>>>(ws_f1, ws_f2, out);
}